// Round 4
// baseline (98.171 us; speedup 1.0000x reference)
//
#include <hip/hip_runtime.h>

// ECConv: out = relu(concat(nf[:8192], mean_seg(relu(EF@We+be).reshape(E,64,64) @ h_src)) @ Wn + bn)
// Sizes: E=65536, N_SRC=32768, N_DST=8192, EDGE_IN=32, NODE_IN=64, HIDDEN=64
// R4: fp32 atomics eliminated (measured memory-side atomic floor ~50-85 G dword/s across R1-R3).
//     CSR sort (int atomics) + edge kernel with plain m[e][h] stores + fused gather-mean final.
//     f32 LDS h_src (no cvt in loop), depth-2 named-register B-frag prefetch.

typedef float f32x4 __attribute__((ext_vector_type(4)));
typedef __bf16 bf16x8 __attribute__((ext_vector_type(8)));
typedef __bf16 bf16x4 __attribute__((ext_vector_type(4)));

#define E_TOT   65536
#define NDST    8192
#define EPW     72    // bf16 hs pad (fallback kernel)
#define EPF     68    // f32 hs pad (fast kernel)

// ================= fast path =================

// ---- prep: blocks 0..63 pack We->(Wp,bp); blocks 64..319 histogram dst ----
// Tile T = d0*4 + ht covers GEMM cols n = (ht*16 + c)*64 + d0, c=0..15.
// B frag for mfma_f32_16x16x32_bf16: lane l holds B[k=(l>>4)*8+j][col=l&15], j=0..7.
__global__ __launch_bounds__(256) void prep_kernel(
    const float* __restrict__ We, const float* __restrict__ be,
    const int* __restrict__ dst, __bf16* __restrict__ Wp, float* __restrict__ bp,
    int* __restrict__ cnt_i) {
  const int b = blockIdx.x;
  if (b < 64) {
    int tid = b * 256 + threadIdx.x;       // 16384 packers
    int T = tid >> 6, l = tid & 63;
    int d0 = T >> 2, ht = T & 3;
    int c = l & 15, kg = l >> 4;
    int ncol = (ht * 16 + c) * 64 + d0;
    bf16x8 v;
#pragma unroll
    for (int j = 0; j < 8; ++j) v[j] = (__bf16)We[(kg * 8 + j) * 4096 + ncol];
    *reinterpret_cast<bf16x8*>(Wp + tid * 8) = v;
    if (l < 16) bp[T * 16 + l] = be[(ht * 16 + l) * 64 + d0];
  } else {
    int e = (b - 64) * 256 + threadIdx.x;
    atomicAdd(&cnt_i[dst[e]], 1);
  }
}

// ---- exclusive scan over 8192 bins, one block; writes off[8193] and cursor copy ----
__global__ __launch_bounds__(256) void scan_kernel(const int* __restrict__ cnt_i,
                                                   int* __restrict__ off,
                                                   int* __restrict__ cursor) {
  __shared__ int part[256];
  const int t = threadIdx.x;
  int loc[32];
  int s = 0;
#pragma unroll
  for (int i = 0; i < 32; ++i) { loc[i] = s; s += cnt_i[t * 32 + i]; }
  part[t] = s;
  __syncthreads();
  if (t == 0) {
    int run = 0;
#pragma unroll 8
    for (int j = 0; j < 256; ++j) { int v = part[j]; part[j] = run; run += v; }
  }
  __syncthreads();
  const int base = part[t];
#pragma unroll
  for (int i = 0; i < 32; ++i) {
    int v = base + loc[i];
    off[t * 32 + i] = v;
    cursor[t * 32 + i] = v;
  }
  if (t == 255) off[8192] = E_TOT;
}

// ---- fill: scatter edge ids into CSR order (int atomics on cursor) ----
__global__ void fill_kernel(const int* __restrict__ dst, int* __restrict__ cursor,
                            int* __restrict__ eid) {
  int e = blockIdx.x * 256 + threadIdx.x;
  int slot = atomicAdd(&cursor[dst[e]], 1);
  eid[slot] = e;
}

// ---- edge compute: m[e][h] = sum_d relu(ef[e]@We[:,h,d] + be[h,d]) * h_src[e][d] ----
// Block: 4 waves, 64 edges; wave w owns h-quadrant ht=w. Plain coalesced stores, no atomics.
__global__ __launch_bounds__(256, 4) void edge2_kernel(
    const float* __restrict__ nf, const float* __restrict__ ef,
    const int* __restrict__ src, const __bf16* __restrict__ Wp,
    const float* __restrict__ bp, float* __restrict__ m) {
  __shared__ float hs[64 * EPF];   // transposed f32 h_src: hs[d][e_local], 17.4 KB
  const int t = threadIdx.x;
  const int eblk = blockIdx.x << 6;

  {
    const int el = t & 63, q = t >> 6;     // 16 d-values per thread
    const int srow = src[eblk + el];
    const f32x4* nfr = (const f32x4*)(nf + (srow << 6) + (q << 4));
#pragma unroll
    for (int i = 0; i < 4; ++i) {
      f32x4 v = nfr[i];
      const int dbase = (q << 4) + i * 4;
      hs[(dbase + 0) * EPF + el] = v[0];
      hs[(dbase + 1) * EPF + el] = v[1];
      hs[(dbase + 2) * EPF + el] = v[2];
      hs[(dbase + 3) * EPF + el] = v[3];
    }
  }

  const int w = t >> 6, l = t & 63;
  const int c = l & 15, g = l >> 4;

  // A fragments: lane holds A[row=c][k=g*8+j] for 4 row-groups of 16 edges
  bf16x8 afr[4];
#pragma unroll
  for (int as = 0; as < 4; ++as) {
    const int e = eblk + as * 16 + c;
    const f32x4* p = (const f32x4*)(ef + (e << 5) + (g << 3));
    f32x4 v0 = p[0], v1 = p[1];
    bf16x8 a;
    a[0] = (__bf16)v0[0]; a[1] = (__bf16)v0[1]; a[2] = (__bf16)v0[2]; a[3] = (__bf16)v0[3];
    a[4] = (__bf16)v1[0]; a[5] = (__bf16)v1[1]; a[6] = (__bf16)v1[2]; a[7] = (__bf16)v1[3];
    afr[as] = a;
  }

  __syncthreads();

  f32x4 acc[4];
#pragma unroll
  for (int i = 0; i < 4; ++i) { acc[i][0] = 0.f; acc[i][1] = 0.f; acc[i][2] = 0.f; acc[i][3] = 0.f; }

  const bf16x8* WpV = (const bf16x8*)Wp;
  const f32x4 zero = {0.f, 0.f, 0.f, 0.f};

  // depth-2 software pipeline on B-frag + bias (named regs, no runtime-indexed arrays)
  bf16x8 bfrA = WpV[(0 * 4 + w) * 64 + l];
  float  bvA  = bp[(0 * 4 + w) * 16 + c];
  bf16x8 bfrB = WpV[(1 * 4 + w) * 64 + l];
  float  bvB  = bp[(1 * 4 + w) * 16 + c];

  for (int d0 = 0; d0 < 64; d0 += 2) {
    {
      const bf16x8 bcur = bfrA;
      const f32x4 cb = {bvA, bvA, bvA, bvA};
      if (d0 + 2 < 64) {
        bfrA = WpV[((d0 + 2) * 4 + w) * 64 + l];
        bvA  = bp[((d0 + 2) * 4 + w) * 16 + c];
      }
#pragma unroll
      for (int as = 0; as < 4; ++as) {
        const f32x4 hvf = *(const f32x4*)&hs[d0 * EPF + as * 16 + (g << 2)];
        f32x4 tmp = __builtin_amdgcn_mfma_f32_16x16x32_bf16(afr[as], bcur, cb, 0, 0, 0);
        tmp = __builtin_elementwise_max(tmp, zero);
        acc[as] = tmp * hvf + acc[as];
      }
    }
    {
      const bf16x8 bcur = bfrB;
      const f32x4 cb = {bvB, bvB, bvB, bvB};
      if (d0 + 3 < 64) {
        bfrB = WpV[((d0 + 3) * 4 + w) * 64 + l];
        bvB  = bp[((d0 + 3) * 4 + w) * 16 + c];
      }
#pragma unroll
      for (int as = 0; as < 4; ++as) {
        const f32x4 hvf = *(const f32x4*)&hs[(d0 + 1) * EPF + as * 16 + (g << 2)];
        f32x4 tmp = __builtin_amdgcn_mfma_f32_16x16x32_bf16(afr[as], bcur, cb, 0, 0, 0);
        tmp = __builtin_elementwise_max(tmp, zero);
        acc[as] = tmp * hvf + acc[as];
      }
    }
  }

  // plain coalesced stores: per instr 4 rows x 16 consecutive floats = 4x64B segments
  const int hbase = (w << 4) + c;
#pragma unroll
  for (int as = 0; as < 4; ++as)
#pragma unroll
    for (int r = 0; r < 4; ++r) {
      const int e = eblk + as * 16 + (g << 2) + r;
      m[(e << 6) + hbase] = acc[as][r];
    }
}

// ---- final: gather-mean per dst (CSR) fused with out = relu(concat@Wn + bn) ----
// Block: 4 waves x 4 rows each = 16 rows. Wn in LDS (32 KB); h_neigh rows staged in LDS.
__global__ __launch_bounds__(256) void final2_kernel(
    const float* __restrict__ nf, const float* __restrict__ m,
    const int* __restrict__ off, const int* __restrict__ eid,
    const float* __restrict__ Wn, const float* __restrict__ bn,
    float* __restrict__ out) {
  __shared__ float wn_s[128 * 64];   // 32 KB
  __shared__ float hn_s[16 * 64];    // 4 KB
  const int t = threadIdx.x;
#pragma unroll
  for (int i = 0; i < 8; ++i)
    ((f32x4*)wn_s)[i * 256 + t] = ((const f32x4*)Wn)[i * 256 + t];

  const int w = t >> 6, h = t & 63;
  const int row0 = blockIdx.x * 16 + w * 4;

  // gather-mean: wave-uniform eid -> coalesced 256B row reads of m
#pragma unroll
  for (int i = 0; i < 4; ++i) {
    const int d = row0 + i;
    const int lo = off[d], hi = off[d + 1];
    float a = 0.f;
    for (int j = lo; j < hi; ++j)
      a += m[(eid[j] << 6) + h];
    hn_s[(w * 4 + i) * 64 + h] = (hi > lo) ? a * (1.f / (float)(hi - lo)) : 0.f;
  }
  __syncthreads();

  const float bv = bn[h];
  float acc[4] = {bv, bv, bv, bv};
#pragma unroll 4
  for (int k = 0; k < 64; ++k) {
    const float wv = wn_s[k * 64 + h];
#pragma unroll
    for (int i = 0; i < 4; ++i)
      acc[i] = fmaf(nf[(row0 + i) * 64 + k], wv, acc[i]);
  }
#pragma unroll 4
  for (int k = 0; k < 64; ++k) {
    const float wv = wn_s[(64 + k) * 64 + h];
#pragma unroll
    for (int i = 0; i < 4; ++i)
      acc[i] = fmaf(hn_s[(w * 4 + i) * 64 + k], wv, acc[i]);
  }
#pragma unroll
  for (int i = 0; i < 4; ++i)
    out[(row0 + i) * 64 + h] = fmaxf(acc[i], 0.f);
}

// ================= fallback path (R3, proven) =================

__global__ void pack_kernel(const float* __restrict__ We, const float* __restrict__ be,
                            __bf16* __restrict__ Wp, float* __restrict__ bp) {
  int tid = blockIdx.x * 256 + threadIdx.x;
  int T = tid >> 6, l = tid & 63;
  int d0 = T >> 2, ht = T & 3;
  int c = l & 15, kg = l >> 4;
  int ncol = (ht * 16 + c) * 64 + d0;
  bf16x8 v;
#pragma unroll
  for (int j = 0; j < 8; ++j) v[j] = (__bf16)We[(kg * 8 + j) * 4096 + ncol];
  *reinterpret_cast<bf16x8*>(Wp + tid * 8) = v;
  if (l < 16) bp[T * 16 + l] = be[(ht * 16 + l) * 64 + d0];
}

__global__ __launch_bounds__(256, 4) void edge_kernel(
    const float* __restrict__ nf, const float* __restrict__ ef,
    const int* __restrict__ src, const int* __restrict__ dst,
    const __bf16* __restrict__ Wp, const float* __restrict__ bp,
    float* __restrict__ msum, float* __restrict__ cnt_g) {
  __shared__ __bf16 hs[64 * EPW];
  const int t = threadIdx.x;
  const int eblk = blockIdx.x << 6;
  {
    const int el = t & 63, q = t >> 6;
    const int srow = src[eblk + el];
    const f32x4* nfr = (const f32x4*)(nf + (srow << 6) + (q << 4));
#pragma unroll
    for (int i = 0; i < 4; ++i) {
      f32x4 v = nfr[i];
      const int dbase = (q << 4) + i * 4;
      hs[(dbase + 0) * EPW + el] = (__bf16)v[0];
      hs[(dbase + 1) * EPW + el] = (__bf16)v[1];
      hs[(dbase + 2) * EPW + el] = (__bf16)v[2];
      hs[(dbase + 3) * EPW + el] = (__bf16)v[3];
    }
  }
  const int w = t >> 6, l = t & 63, c = l & 15, g = l >> 4;
  bf16x8 afr[4];
#pragma unroll
  for (int as = 0; as < 4; ++as) {
    const int e = eblk + as * 16 + c;
    const f32x4* p = (const f32x4*)(ef + (e << 5) + (g << 3));
    f32x4 v0 = p[0], v1 = p[1];
    bf16x8 a;
    a[0] = (__bf16)v0[0]; a[1] = (__bf16)v0[1]; a[2] = (__bf16)v0[2]; a[3] = (__bf16)v0[3];
    a[4] = (__bf16)v1[0]; a[5] = (__bf16)v1[1]; a[6] = (__bf16)v1[2]; a[7] = (__bf16)v1[3];
    afr[as] = a;
  }
  __syncthreads();
  f32x4 acc[4];
#pragma unroll
  for (int i = 0; i < 4; ++i) { acc[i][0]=0.f; acc[i][1]=0.f; acc[i][2]=0.f; acc[i][3]=0.f; }
  const bf16x8* WpV = (const bf16x8*)Wp;
  const f32x4 zero = {0.f, 0.f, 0.f, 0.f};
#pragma unroll 4
  for (int d0 = 0; d0 < 64; ++d0) {
    const int T = d0 * 4 + w;
    const bf16x8 bfr = WpV[T * 64 + l];
    const float bv = bp[T * 16 + c];
    const f32x4 cb = {bv, bv, bv, bv};
#pragma unroll
    for (int as = 0; as < 4; ++as) {
      const bf16x4 hv = *(const bf16x4*)&hs[d0 * EPW + as * 16 + (g << 2)];
      const f32x4 hvf = {(float)hv[0], (float)hv[1], (float)hv[2], (float)hv[3]};
      f32x4 tmp = __builtin_amdgcn_mfma_f32_16x16x32_bf16(afr[as], bfr, cb, 0, 0, 0);
      tmp = __builtin_elementwise_max(tmp, zero);
      acc[as] = tmp * hvf + acc[as];
    }
  }
#pragma unroll
  for (int as = 0; as < 4; ++as)
#pragma unroll
    for (int r = 0; r < 4; ++r) {
      const int e = eblk + as * 16 + (g << 2) + r;
      const int dd = dst[e];
      unsafeAtomicAdd(msum + (dd << 6) + (w << 4) + c, acc[as][r]);
      if (w == 0 && c == 0) unsafeAtomicAdd(cnt_g + dd, 1.0f);
    }
}

__global__ __launch_bounds__(256) void final_kernel(
    const float* __restrict__ nf, const float* __restrict__ msum,
    const float* __restrict__ cnt, const float* __restrict__ Wn,
    const float* __restrict__ bn, float* __restrict__ out) {
  __shared__ float wn_s[128 * 64];
  const int t = threadIdx.x;
#pragma unroll
  for (int i = 0; i < 8; ++i)
    ((f32x4*)wn_s)[i * 256 + t] = ((const f32x4*)Wn)[i * 256 + t];
  __syncthreads();
  const int w = t >> 6, h = t & 63;
  const int row0 = blockIdx.x * 16 + w * 4;
  const float bv = bn[h];
  float acc[4] = {bv, bv, bv, bv};
  float s[4];
#pragma unroll
  for (int i = 0; i < 4; ++i) {
    const float cv = cnt[row0 + i];
    s[i] = cv > 0.f ? 1.f / cv : 0.f;
  }
#pragma unroll 4
  for (int k = 0; k < 64; ++k) {
    const float wv = wn_s[k * 64 + h];
#pragma unroll
    for (int i = 0; i < 4; ++i) acc[i] = fmaf(nf[(row0 + i) * 64 + k], wv, acc[i]);
  }
#pragma unroll 4
  for (int k = 0; k < 64; ++k) {
    const float wv = wn_s[(64 + k) * 64 + h];
#pragma unroll
    for (int i = 0; i < 4; ++i) acc[i] = fmaf(msum[(row0 + i) * 64 + k] * s[i], wv, acc[i]);
  }
#pragma unroll
  for (int i = 0; i < 4; ++i) out[(row0 + i) * 64 + h] = fmaxf(acc[i], 0.f);
}

// ================= launcher =================

extern "C" void kernel_launch(void* const* d_in, const int* in_sizes, int n_in,
                              void* d_out, int out_size, void* d_ws, size_t ws_size,
                              hipStream_t stream) {
  const float* nf  = (const float*)d_in[0];
  const float* ef  = (const float*)d_in[1];
  const int*   src = (const int*)d_in[2];
  const int*   dst = (const int*)d_in[3];
  const float* We  = (const float*)d_in[4];
  const float* be  = (const float*)d_in[5];
  const float* Wn  = (const float*)d_in[6];
  const float* bn  = (const float*)d_in[7];
  float* out = (float*)d_out;
  char* ws = (char*)d_ws;

  // fast-path layout
  const size_t OFF_M      = 0;                       // 16777216 B  (m: E*64 f32)
  const size_t OFF_OFF    = 16777216;                // 36864 B    (off: 8193 int, padded)
  const size_t OFF_CURSOR = OFF_OFF + 36864;         // 32768 B
  const size_t OFF_CNTI   = OFF_CURSOR + 32768;      // 32768 B
  const size_t OFF_EID    = OFF_CNTI + 32768;        // 262144 B
  const size_t OFF_WP     = OFF_EID + 262144;        // 262144 B
  const size_t OFF_BP     = OFF_WP + 262144;         // 16384 B
  const size_t NEED_FAST  = OFF_BP + 16384;          // ~17.42 MB

  if (ws_size >= NEED_FAST) {
    float*  m      = (float*)(ws + OFF_M);
    int*    off    = (int*)(ws + OFF_OFF);
    int*    cursor = (int*)(ws + OFF_CURSOR);
    int*    cnt_i  = (int*)(ws + OFF_CNTI);
    int*    eid    = (int*)(ws + OFF_EID);
    __bf16* Wp     = (__bf16*)(ws + OFF_WP);
    float*  bp     = (float*)(ws + OFF_BP);

    hipMemsetAsync(cnt_i, 0, 32768, stream);
    prep_kernel<<<320, 256, 0, stream>>>(We, be, dst, Wp, bp, cnt_i);
    scan_kernel<<<1, 256, 0, stream>>>(cnt_i, off, cursor);
    fill_kernel<<<E_TOT / 256, 256, 0, stream>>>(dst, cursor, eid);
    edge2_kernel<<<E_TOT / 64, 256, 0, stream>>>(nf, ef, src, Wp, bp, m);
    final2_kernel<<<NDST / 16, 256, 0, stream>>>(nf, m, off, eid, Wn, bn, out);
  } else {
    // R3 fallback (atomic path)
    float* msum = (float*)ws;
    float* cnt  = (float*)(ws + 2097152);
    const size_t need = 2097152 + 32768 + 262144 + 16384;
    __bf16* Wp;
    float*  bp;
    if (ws_size >= need) {
      Wp = (__bf16*)(ws + 2097152 + 32768);
      bp = (float*)(ws + 2097152 + 32768 + 262144);
    } else {
      Wp = (__bf16*)d_out;
      bp = (float*)((char*)d_out + 262144);
    }
    hipMemsetAsync(msum, 0, 2097152 + 32768, stream);
    pack_kernel<<<64, 256, 0, stream>>>(We, be, Wp, bp);
    edge_kernel<<<E_TOT / 64, 256, 0, stream>>>(nf, ef, src, dst, Wp, bp, msum, cnt);
    final_kernel<<<NDST / 16, 256, 0, stream>>>(nf, msum, cnt, Wn, bn, out);
  }
}